// Round 8
// baseline (156.567 us; speedup 1.0000x reference)
//
#include <hip/hip_runtime.h>
#include <stdint.h>

// Problem: B=32, S=2048, E2=1024, D=512
//   c[b][d]    = b_att[d] + sum_k dec[b][k] * W_att[1024+k][d]
//   att[b][s]  = sum_d tanh( sum_e x[b][s][e]*W_att[e][d] + c[b][d] ) * v[d]
//   w          = softmax(att, axis=s)
//   out[b][e]  = sum_s w[b][s] * x[b][s][e]
//
// ws layout: [0,256K) attention f32[65536]; [256K,320K) cbias f32[16384];
//            [320K,320K+1MiB) W_enc bf16 "fragment image":
//   16B unit index  u = c*2048 + wn*256 + nf*64 + lane   (c=K-chunk of 32)
//   holds W_enc[c*32 + (lane>>4)*8 + j][wn*64 + nf*16 + (lane&15)], j=0..7
// => wave wn's B-fragment for (c,nf) is ONE coalesced 1KB global load
//    (global_load_dwordx4 per lane), exactly in MFMA B-operand layout.

typedef __attribute__((ext_vector_type(8))) __bf16 bf16x8;
typedef __attribute__((ext_vector_type(4))) float f32x4;

__device__ __forceinline__ uint16_t f32_to_bf16_rne(float f) {
  union { float f; uint32_t u; } v; v.f = f;
  uint32_t u = v.u;
  return (uint16_t)((u + 0x7FFFu + ((u >> 16) & 1u)) >> 16);
}

__device__ __forceinline__ float tanh_fast(float x) {
  float e = __expf(2.0f * x);
  return 1.0f - 2.0f * __builtin_amdgcn_rcpf(e + 1.0f);
}

// ---------------- Kernel A: prep (image layout unchanged from round 7) ----------------
__global__ __launch_bounds__(256) void prep_kernel(
    const float* __restrict__ dec,   // (32,512)
    const float* __restrict__ Watt,  // (1536,512)
    const float* __restrict__ batt,  // (512)
    float* __restrict__ cbias,       // ws (32*512)
    uint16_t* __restrict__ Wb,       // ws (1 MiB fragment image)
    float* __restrict__ out)         // d_out (32768) -> zero
{
  const int t = blockIdx.x * 256 + threadIdx.x;  // [0,16384)

  for (int i = t; i < 32768; i += 16384) out[i] = 0.0f;

  // cbias: one output per thread. b = t>>9, d = t&511.
  {
    const int b = t >> 9, d = t & 511;
    const float* wd = Watt + 1024 * 512 + d;
    const float* dv = dec + b * 512;
    float s0 = 0.f, s1 = 0.f, s2 = 0.f, s3 = 0.f;
    #pragma unroll 4
    for (int k = 0; k < 512; k += 4) {
      s0 += dv[k + 0] * wd[(k + 0) * 512];
      s1 += dv[k + 1] * wd[(k + 1) * 512];
      s2 += dv[k + 2] * wd[(k + 2) * 512];
      s3 += dv[k + 3] * wd[(k + 3) * 512];
    }
    cbias[t] = batt[d] + ((s0 + s1) + (s2 + s3));
  }

  // W fragment image: 65536 16-byte units, 4 per thread.
  uint4* WbV = (uint4*)Wb;
  #pragma unroll
  for (int i = 0; i < 4; ++i) {
    const int u   = t + 16384 * i;    // [0,65536)
    const int c   = u >> 11;          // K-chunk (32-k granularity)
    const int rem = u & 2047;
    const int wn  = rem >> 8;         // 0..7
    const int nf  = (rem >> 6) & 3;   // 0..3
    const int ln  = rem & 63;         // lane
    const int kb  = c * 32 + ((ln >> 4) << 3);
    const int d   = wn * 64 + nf * 16 + (ln & 15);
    uint32_t h[8];
    #pragma unroll
    for (int kk = 0; kk < 8; ++kk) {
      float f = Watt[(size_t)(kb + kk) * 512 + d];
      h[kk] = f32_to_bf16_rne(f);
    }
    uint4 val;
    val.x = h[0] | (h[1] << 16);
    val.y = h[2] | (h[3] << 16);
    val.z = h[4] | (h[5] << 16);
    val.w = h[6] | (h[7] << 16);
    WbV[u] = val;
  }
}

// ---------------- Kernel B: fused energy GEMM + tanh + dot(v), v8 ----------------
// v8 = v7 with BK=64 per barrier interval (2 K-chunks): 32 MFMA per barrier
// instead of 16 -- halves the rendezvous/staging-wait count. B stays in regs
// (single-buffered 8 frags, loaded right after the barrier; A ds_reads +
// chunk-0 MFMAs hide the L2 latency of chunk-1's frags). LDS = A only,
// 64x64 bf16 dbuf (16 KB). 1024 blocks x 512 thr; ~124 unified regs ->
// 4 waves/SIMD, 2 independent blocks/CU.
__global__ __launch_bounds__(512, 4) void energy_kernel(
    const float* __restrict__ x,       // (65536,1024)
    const uint16_t* __restrict__ Wb,   // fragment image (1 MiB)
    const float* __restrict__ cbias,   // (32,512)
    const float* __restrict__ vvec,    // (512)
    float* __restrict__ att)           // (65536), fully overwritten
{
  __shared__ __align__(16) uint8_t AL[2][64 * 128];    // 2 x 8 KB : A 64r x 64k bf16

  const int tid  = threadIdx.x;
  const int lane = tid & 63;
  const int wave = tid >> 6;           // 0..7 = wn (64-col group)
  const int l15  = lane & 15;
  const int l4   = lane >> 4;
  const int brow0 = blockIdx.x * 64;
  const int b     = brow0 >> 11;

  // A staging: 2 float4/thread. r_st = tid>>3 in [0,64); q in {q_st, q_st+8}.
  // LDS row = 128 B; swizzle byte = r*128 + ((q*8) ^ ((r&7)<<4)).
  const int r_st = tid >> 3, q_st = tid & 7;
  const int aoff0 = r_st * 128 + ((q_st * 8) ^ ((r_st & 7) << 4));
  const int aoff1 = r_st * 128 + (((q_st + 8) * 8) ^ ((r_st & 7) << 4));
  const float* asrc = x + (size_t)(brow0 + r_st) * 1024 + q_st * 4;  // +32 floats for q+8
  // this wave's B slice: 4 frags x 1 KB per 32-k chunk; interval stride 64 KB
  const uint8_t* wslice = (const uint8_t*)Wb + (size_t)wave * 4096 + (size_t)lane * 16;

  f32x4 acc[4][4];
  #pragma unroll
  for (int mf = 0; mf < 4; ++mf)
    #pragma unroll
    for (int nf = 0; nf < 4; ++nf)
      acc[mf][nf] = (f32x4){0.f, 0.f, 0.f, 0.f};

  // prologue: av(0) pair
  float4 av0 = *(const float4*)(asrc);
  float4 av1 = *(const float4*)(asrc + 32);

  for (int i = 0; i < 16; ++i) {       // 16 intervals x BK=64
    uint8_t* Ab = AL[i & 1];

    // write A(i) from av pair (compiler: counted vmcnt for av only)
    {
      uint32_t lo = (uint32_t)f32_to_bf16_rne(av0.x) | ((uint32_t)f32_to_bf16_rne(av0.y) << 16);
      uint32_t hi = (uint32_t)f32_to_bf16_rne(av0.z) | ((uint32_t)f32_to_bf16_rne(av0.w) << 16);
      *(uint2*)(Ab + aoff0) = make_uint2(lo, hi);
      lo = (uint32_t)f32_to_bf16_rne(av1.x) | ((uint32_t)f32_to_bf16_rne(av1.y) << 16);
      hi = (uint32_t)f32_to_bf16_rne(av1.z) | ((uint32_t)f32_to_bf16_rne(av1.w) << 16);
      *(uint2*)(Ab + aoff1) = make_uint2(lo, hi);
    }
    if (i < 15) {                      // issue av(i+1); stays in flight across barrier
      av0 = *(const float4*)(asrc + (i + 1) * 64);
      av1 = *(const float4*)(asrc + (i + 1) * 64 + 32);
    }
    asm volatile("s_waitcnt lgkmcnt(0)" ::: "memory");   // A writes visible
    __builtin_amdgcn_s_barrier();
    asm volatile("" ::: "memory");

    // load this interval's 8 B-fragments (chunk 2i then 2i+1); used below —
    // compiler inserts counted vmcnt before first MFMA use.
    const bf16x8* bs = (const bf16x8*)(wslice + (size_t)i * 65536);
    bf16x8 b0 = bs[0],    b1 = bs[64],     b2 = bs[128],     b3 = bs[192];
    bf16x8 b4 = bs[2048], b5 = bs[2048+64], b6 = bs[2048+128], b7 = bs[2048+192];

    // chunk 0 (k = 64i .. +32): 4 ds_read + 16 MFMA
    #pragma unroll
    for (int mf = 0; mf < 4; ++mf) {
      const int r = mf * 16 + l15;
      bf16x8 afm = *(const bf16x8*)(Ab + r * 128 + ((l4 * 16) ^ ((r & 7) << 4)));
      acc[mf][0] = __builtin_amdgcn_mfma_f32_16x16x32_bf16(afm, b0, acc[mf][0], 0, 0, 0);
      acc[mf][1] = __builtin_amdgcn_mfma_f32_16x16x32_bf16(afm, b1, acc[mf][1], 0, 0, 0);
      acc[mf][2] = __builtin_amdgcn_mfma_f32_16x16x32_bf16(afm, b2, acc[mf][2], 0, 0, 0);
      acc[mf][3] = __builtin_amdgcn_mfma_f32_16x16x32_bf16(afm, b3, acc[mf][3], 0, 0, 0);
    }
    // chunk 1 (k = 64i+32 .. +32)
    #pragma unroll
    for (int mf = 0; mf < 4; ++mf) {
      const int r = mf * 16 + l15;
      bf16x8 afm = *(const bf16x8*)(Ab + r * 128 + (((64 + l4 * 16)) ^ ((r & 7) << 4)));
      acc[mf][0] = __builtin_amdgcn_mfma_f32_16x16x32_bf16(afm, b4, acc[mf][0], 0, 0, 0);
      acc[mf][1] = __builtin_amdgcn_mfma_f32_16x16x32_bf16(afm, b5, acc[mf][1], 0, 0, 0);
      acc[mf][2] = __builtin_amdgcn_mfma_f32_16x16x32_bf16(afm, b6, acc[mf][2], 0, 0, 0);
      acc[mf][3] = __builtin_amdgcn_mfma_f32_16x16x32_bf16(afm, b7, acc[mf][3], 0, 0, 0);
    }
  }

  // ---- epilogue: tanh + dot(v); LDS-atomic reduce across the 8 waves ----
  float cb[4], vv[4];
  #pragma unroll
  for (int nf = 0; nf < 4; ++nf) {
    const int d = wave * 64 + nf * 16 + l15;
    cb[nf] = cbias[b * 512 + d];
    vv[nf] = vvec[d];
  }

  __syncthreads();                       // all waves done reading AL
  float* red = (float*)AL;               // reuse 256 B of A space
  if (tid < 64) red[tid] = 0.0f;
  __syncthreads();

  #pragma unroll
  for (int mf = 0; mf < 4; ++mf) {
    float s[4] = {0.f, 0.f, 0.f, 0.f};
    #pragma unroll
    for (int nf = 0; nf < 4; ++nf) {
      #pragma unroll
      for (int j = 0; j < 4; ++j) {
        const float e = acc[mf][nf][j] + cb[nf];
        s[j] += tanh_fast(e) * vv[nf];
      }
    }
    #pragma unroll
    for (int j = 0; j < 4; ++j) {
      float r = s[j];
      r += __shfl_xor(r, 1);
      r += __shfl_xor(r, 2);
      r += __shfl_xor(r, 4);
      r += __shfl_xor(r, 8);
      if (l15 == 0) atomicAdd(&red[mf * 16 + 4 * l4 + j], r);
    }
  }
  __syncthreads();
  if (tid < 64) att[brow0 + tid] = red[tid];
}

// ---------------- Kernel C: softmax over S (in place) ----------------
__global__ __launch_bounds__(256) void softmax_kernel(float* __restrict__ att) {
  const int b = blockIdx.x;
  float* row = att + b * 2048;
  const int tid = threadIdx.x;
  __shared__ float redm[4], reds[4];

  float vals[8];
  float m = -1e30f;
  #pragma unroll
  for (int i = 0; i < 8; ++i) { vals[i] = row[tid + 256 * i]; m = fmaxf(m, vals[i]); }
  #pragma unroll
  for (int msk = 1; msk < 64; msk <<= 1) m = fmaxf(m, __shfl_xor(m, msk));
  if ((tid & 63) == 0) redm[tid >> 6] = m;
  __syncthreads();
  m = fmaxf(fmaxf(redm[0], redm[1]), fmaxf(redm[2], redm[3]));

  float s = 0.f;
  #pragma unroll
  for (int i = 0; i < 8; ++i) { vals[i] = __expf(vals[i] - m); s += vals[i]; }
  #pragma unroll
  for (int msk = 1; msk < 64; msk <<= 1) s += __shfl_xor(s, msk);
  if ((tid & 63) == 0) reds[tid >> 6] = s;
  __syncthreads();
  const float inv = 1.0f / (((reds[0] + reds[1]) + (reds[2] + reds[3])));
  #pragma unroll
  for (int i = 0; i < 8; ++i) row[tid + 256 * i] = vals[i] * inv;
}

// ---------------- Kernel D: context = w @ x ----------------
// 2048 blocks (32 b x 64 s-chunks of 32); more blocks = more latency hiding.
__global__ __launch_bounds__(256) void context_kernel(
    const float* __restrict__ x,   // (65536,1024)
    const float* __restrict__ w,   // (32,2048)
    float* __restrict__ out)       // (32,1024), pre-zeroed
{
  const int blk = blockIdx.x;
  const int b = blk >> 6, sc = blk & 63;
  const int tid = threadIdx.x;
  const float* xb = x + ((size_t)(b * 2048 + sc * 32)) * 1024 + tid * 4;
  const float* wb = w + b * 2048 + sc * 32;

  float4 acc = {0.f, 0.f, 0.f, 0.f};
  #pragma unroll 4
  for (int si = 0; si < 32; ++si) {
    const float ww = wb[si];
    const float4 xv = *(const float4*)(xb + (size_t)si * 1024);
    acc.x += ww * xv.x;
    acc.y += ww * xv.y;
    acc.z += ww * xv.z;
    acc.w += ww * xv.w;
  }
  float* o = out + b * 1024 + tid * 4;
  atomicAdd(o + 0, acc.x);
  atomicAdd(o + 1, acc.y);
  atomicAdd(o + 2, acc.z);
  atomicAdd(o + 3, acc.w);
}

extern "C" void kernel_launch(void* const* d_in, const int* in_sizes, int n_in,
                              void* d_out, int out_size, void* d_ws, size_t ws_size,
                              hipStream_t stream) {
  const float* x    = (const float*)d_in[0];  // (32,2048,1024)
  const float* dec  = (const float*)d_in[1];  // (32,512)
  const float* Watt = (const float*)d_in[2];  // (1536,512)
  const float* batt = (const float*)d_in[3];  // (512)
  const float* v    = (const float*)d_in[4];  // (512)
  float* out = (float*)d_out;

  uint8_t* ws = (uint8_t*)d_ws;
  float*    att   = (float*)ws;                        // 256 KB
  float*    cbias = (float*)(ws + 256 * 1024);         // 64 KB
  uint16_t* Wb    = (uint16_t*)(ws + 320 * 1024);      // 1 MiB

  prep_kernel<<<64, 256, 0, stream>>>(dec, Watt, batt, cbias, Wb, out);
  energy_kernel<<<1024, 512, 0, stream>>>(x, Wb, cbias, v, att);
  softmax_kernel<<<32, 256, 0, stream>>>(att);
  context_kernel<<<2048, 256, 0, stream>>>(x, att, out);
}